// Round 1
// baseline (3040.860 us; speedup 1.0000x reference)
//
#include <hip/hip_runtime.h>
#include <math.h>

#define TTOK   8192
#define HDIM   2048
#define MDIM   1408
#define NEXP   32
#define TOPK   6
#define SHDIM  2816
#define RCAP   53248   // 49152 + 32*127 rounded up to 128
#define MAXRT  416

typedef unsigned short u16;
typedef __bf16 bf16x8 __attribute__((ext_vector_type(8)));
typedef float f32x4 __attribute__((ext_vector_type(4)));

__device__ __forceinline__ void gl2lds16(const void* g, void* l) {
  __builtin_amdgcn_global_load_lds(
      (const __attribute__((address_space(1))) void*)g,
      (__attribute__((address_space(3))) void*)l, 16, 0, 0);
}

__device__ __forceinline__ u16 f2bf(float f) {
  union { float f; unsigned u; } v; v.f = f;
  unsigned r = v.u + 0x7fffu + ((v.u >> 16) & 1u);
  return (u16)(r >> 16);
}
__device__ __forceinline__ float bf2f(u16 b) {
  union { unsigned u; float f; } v; v.u = ((unsigned)b) << 16;
  return v.f;
}

// ---------------- conversion kernels ----------------

__global__ __launch_bounds__(256) void cvt_f32_bf16(
    const float* __restrict__ in, u16* __restrict__ out, long n) {
  long i = ((long)blockIdx.x * 256 + threadIdx.x) * 4;
  if (i >= n) return;
  float4 v = *(const float4*)&in[i];
  ushort4 o;
  o.x = f2bf(v.x); o.y = f2bf(v.y); o.z = f2bf(v.z); o.w = f2bf(v.w);
  *(ushort4*)&out[i] = o;
}

// in: [E][Kd][N] f32  ->  out: [E][N][Kd] bf16   (grid: (N/32, Kd/32, E), block 256)
__global__ __launch_bounds__(256) void tcvt(
    const float* __restrict__ in, u16* __restrict__ out, int Kd, int N) {
  __shared__ u16 tile[32][33];
  long base = (long)blockIdx.z * Kd * N;
  int n0 = blockIdx.x * 32, k0 = blockIdx.y * 32;
  int tx = threadIdx.x & 31, ty = threadIdx.x >> 5;  // 32x8
  #pragma unroll
  for (int i = 0; i < 4; i++) {
    int kk = ty + i * 8;
    tile[kk][tx] = f2bf(in[base + (long)(k0 + kk) * N + n0 + tx]);
  }
  __syncthreads();
  #pragma unroll
  for (int i = 0; i < 4; i++) {
    int nn = ty + i * 8;
    out[base + (long)(n0 + nn) * Kd + k0 + tx] = tile[tx][nn];
  }
}

// ---------------- routing ----------------

__global__ void zero32(int* __restrict__ p) { p[threadIdx.x] = 0; }

__global__ __launch_bounds__(256) void gate_route(
    const float* __restrict__ x, const float* __restrict__ gw,
    float* __restrict__ wtop, int* __restrict__ sel, int* __restrict__ counts) {
  __shared__ float sx[4][HDIM];
  __shared__ float part[4][8][32];
  __shared__ float sig[4][NEXP];
  int tid = threadIdx.x;
  long tbase = (long)blockIdx.x * 4;
  for (int i = tid; i < 4 * HDIM; i += 256) {
    int tok = i >> 11, col = i & (HDIM - 1);
    sx[tok][col] = x[(tbase + tok) * HDIM + col];
  }
  __syncthreads();
  {
    int e = tid & 31, ch = tid >> 5;
    float p0 = 0, p1 = 0, p2 = 0, p3 = 0;
    int i0 = ch * 256;
    for (int i = i0; i < i0 + 256; i++) {
      float g = gw[i * NEXP + e];
      p0 += sx[0][i] * g; p1 += sx[1][i] * g;
      p2 += sx[2][i] * g; p3 += sx[3][i] * g;
    }
    part[0][ch][e] = p0; part[1][ch][e] = p1;
    part[2][ch][e] = p2; part[3][ch][e] = p3;
  }
  __syncthreads();
  if (tid < 128) {
    int tok = tid >> 5, e = tid & 31;
    float s = 0;
    #pragma unroll
    for (int c = 0; c < 8; c++) s += part[tok][c][e];
    sig[tok][e] = 1.f / (1.f + expf(-s));
  }
  __syncthreads();
  if (tid < 4) {
    int tok = tid;
    long t = tbase + tok;
    float gm[4];
    #pragma unroll
    for (int g = 0; g < 4; g++) {
      float m = sig[tok][g * 8];
      for (int j = 1; j < 8; j++) m = fmaxf(m, sig[tok][g * 8 + j]);
      gm[g] = m;
    }
    int g1 = 0;
    for (int g = 1; g < 4; g++) if (gm[g] > gm[g1]) g1 = g;
    int g2 = -1;
    for (int g = 0; g < 4; g++) {
      if (g == g1) continue;
      if (g2 < 0 || gm[g] > gm[g2]) g2 = g;
    }
    bool chosen[NEXP];
    for (int e = 0; e < NEXP; e++) chosen[e] = false;
    float ssum = 0.f;
    float wv[TOPK]; int sv[TOPK];
    for (int k = 0; k < TOPK; k++) {
      int best = -1; float bv = 0.f;
      for (int e = 0; e < NEXP; e++) {
        int grp = e >> 3;
        if (grp != g1 && grp != g2) continue;
        if (chosen[e]) continue;
        float v = sig[tok][e];
        if (best < 0 || v > bv) { best = e; bv = v; }
      }
      chosen[best] = true;
      sv[k] = best; wv[k] = bv; ssum += bv;
      atomicAdd(&counts[best], 1);
    }
    float inv = 1.f / ssum;
    for (int k = 0; k < TOPK; k++) {
      sel[t * TOPK + k] = sv[k];
      wtop[t * TOPK + k] = wv[k] * inv;
    }
  }
}

__global__ void scan_k(const int* __restrict__ counts, int* __restrict__ padoff,
                       int* __restrict__ cursor, int2* __restrict__ rtiles,
                       int2* __restrict__ stiles) {
  if (threadIdx.x != 0) return;
  int off = 0, tc = 0;
  for (int e = 0; e < NEXP; e++) {
    padoff[e] = off;
    cursor[e] = 0;
    int nt = (counts[e] + 127) >> 7;
    for (int i = 0; i < nt; i++) { rtiles[tc] = make_int2(e, off + i * 128); tc++; }
    off += nt << 7;
  }
  for (; tc < MAXRT; tc++) rtiles[tc] = make_int2(-1, 0);
  for (int i = 0; i < TTOK / 128; i++) stiles[i] = make_int2(0, i * 128);
}

__global__ __launch_bounds__(256) void fill_rt(int* __restrict__ rt) {
  rt[blockIdx.x * 256 + threadIdx.x] = 0;
}

__global__ __launch_bounds__(256) void assign_k(
    const int* __restrict__ sel, const int* __restrict__ padoff,
    int* __restrict__ cursor, int* __restrict__ slot_of, int* __restrict__ rowTok) {
  int idx = blockIdx.x * 256 + threadIdx.x;
  int e = sel[idx];
  int pos = atomicAdd(&cursor[e], 1);
  int s = padoff[e] + pos;
  slot_of[idx] = s;
  rowTok[s] = idx / TOPK;
}

// ---------------- GEMMs (128x128 tile, 16x16x32 bf16 MFMA, 4 waves) ----------------

// C-tile = silu(A@Bg) * (A@Bu), bf16 out. A rows optionally gathered via rowTok.
__global__ __launch_bounds__(256, 2)
void gemm_gateup(const u16* __restrict__ A, const int* __restrict__ rowTok,
                 const u16* __restrict__ Bg, const u16* __restrict__ Bu,
                 long bStride, u16* __restrict__ Hout, int ldH, int Kd,
                 const int2* __restrict__ tiles) {
  __shared__ u16 sA[128 * 32];
  __shared__ u16 sG[128 * 32];
  __shared__ u16 sU[128 * 32];

  int2 te = tiles[blockIdx.y];
  if (te.x < 0) return;
  const int row0 = te.y;
  const long n0 = (long)blockIdx.x * 128;

  const int tid = threadIdx.x;
  const int lane = tid & 63;
  const int wave = tid >> 6;
  const int wm = wave & 1, wn = wave >> 1;
  const int l16 = lane & 15, quad = lane >> 4;

  const u16* bg0 = Bg + (long)te.x * bStride + n0 * Kd;
  const u16* bu0 = Bu + (long)te.x * bStride + n0 * Kd;

  const int cA = tid, cB = tid + 256;         // chunk id: row = c>>2, k8 = (c&3)*8
  const int rA = cA >> 2, kA = (cA & 3) << 3;
  const int rB = cB >> 2, kB = (cB & 3) << 3;
  long arA = rowTok ? (long)rowTok[row0 + rA] : (long)(row0 + rA);
  long arB = rowTok ? (long)rowTok[row0 + rB] : (long)(row0 + rB);
  const u16* gA0 = A + arA * Kd + kA;
  const u16* gA1 = A + arB * Kd + kB;
  const u16* gG0 = bg0 + (long)rA * Kd + kA;
  const u16* gG1 = bg0 + (long)rB * Kd + kB;
  const u16* gU0 = bu0 + (long)rA * Kd + kA;
  const u16* gU1 = bu0 + (long)rB * Kd + kB;
  u16* lA0 = &sA[cA * 8]; u16* lA1 = &sA[cB * 8];
  u16* lG0 = &sG[cA * 8]; u16* lG1 = &sG[cB * 8];
  u16* lU0 = &sU[cA * 8]; u16* lU1 = &sU[cB * 8];

  f32x4 accg[4][4], accu[4][4];
  #pragma unroll
  for (int i = 0; i < 4; i++)
    #pragma unroll
    for (int j = 0; j < 4; j++) {
      accg[i][j] = f32x4{0.f, 0.f, 0.f, 0.f};
      accu[i][j] = f32x4{0.f, 0.f, 0.f, 0.f};
    }

  int aoff[4], boff[4];
  #pragma unroll
  for (int i = 0; i < 4; i++) aoff[i] = (wm * 64 + i * 16 + l16) * 32 + quad * 8;
  #pragma unroll
  for (int j = 0; j < 4; j++) boff[j] = (wn * 64 + j * 16 + l16) * 32 + quad * 8;

  for (int k0 = 0; k0 < Kd; k0 += 32) {
    __syncthreads();
    gl2lds16(gA0 + k0, lA0); gl2lds16(gA1 + k0, lA1);
    gl2lds16(gG0 + k0, lG0); gl2lds16(gG1 + k0, lG1);
    gl2lds16(gU0 + k0, lU0); gl2lds16(gU1 + k0, lU1);
    __syncthreads();
    bf16x8 fa[4], fg[4], fu[4];
    #pragma unroll
    for (int i = 0; i < 4; i++) fa[i] = *(const bf16x8*)&sA[aoff[i]];
    #pragma unroll
    for (int j = 0; j < 4; j++) {
      fg[j] = *(const bf16x8*)&sG[boff[j]];
      fu[j] = *(const bf16x8*)&sU[boff[j]];
    }
    #pragma unroll
    for (int i = 0; i < 4; i++)
      #pragma unroll
      for (int j = 0; j < 4; j++) {
        accg[i][j] = __builtin_amdgcn_mfma_f32_16x16x32_bf16(fa[i], fg[j], accg[i][j], 0, 0, 0);
        accu[i][j] = __builtin_amdgcn_mfma_f32_16x16x32_bf16(fa[i], fu[j], accu[i][j], 0, 0, 0);
      }
  }

  #pragma unroll
  for (int i = 0; i < 4; i++)
    #pragma unroll
    for (int j = 0; j < 4; j++)
      #pragma unroll
      for (int r = 0; r < 4; r++) {
        float g = accg[i][j][r], u = accu[i][j][r];
        float h = g / (1.f + __expf(-g)) * u;   // silu(g)*u
        long rr = row0 + wm * 64 + i * 16 + quad * 4 + r;
        long cc = n0 + wn * 64 + j * 16 + l16;
        Hout[rr * ldH + cc] = f2bf(h);
      }
}

// C = A@B; writes bf16 (outB) or fp32 (outF), exactly one non-null.
__global__ __launch_bounds__(256, 3)
void gemm_down(const u16* __restrict__ A, const u16* __restrict__ B,
               long bStride, u16* __restrict__ outB, float* __restrict__ outF,
               int ldO, int Kd, const int2* __restrict__ tiles) {
  __shared__ u16 sA[128 * 32];
  __shared__ u16 sB[128 * 32];

  int2 te = tiles[blockIdx.y];
  if (te.x < 0) return;
  const int row0 = te.y;
  const long n0 = (long)blockIdx.x * 128;

  const int tid = threadIdx.x;
  const int lane = tid & 63;
  const int wave = tid >> 6;
  const int wm = wave & 1, wn = wave >> 1;
  const int l16 = lane & 15, quad = lane >> 4;

  const u16* b0 = B + (long)te.x * bStride + n0 * Kd;
  const int cA = tid, cB = tid + 256;
  const int rA = cA >> 2, kA = (cA & 3) << 3;
  const int rB = cB >> 2, kB = (cB & 3) << 3;
  const u16* gA0 = A + (long)(row0 + rA) * Kd + kA;
  const u16* gA1 = A + (long)(row0 + rB) * Kd + kB;
  const u16* gB0 = b0 + (long)rA * Kd + kA;
  const u16* gB1 = b0 + (long)rB * Kd + kB;
  u16* lA0 = &sA[cA * 8]; u16* lA1 = &sA[cB * 8];
  u16* lB0 = &sB[cA * 8]; u16* lB1 = &sB[cB * 8];

  f32x4 acc[4][4];
  #pragma unroll
  for (int i = 0; i < 4; i++)
    #pragma unroll
    for (int j = 0; j < 4; j++) acc[i][j] = f32x4{0.f, 0.f, 0.f, 0.f};

  int aoff[4], boff[4];
  #pragma unroll
  for (int i = 0; i < 4; i++) aoff[i] = (wm * 64 + i * 16 + l16) * 32 + quad * 8;
  #pragma unroll
  for (int j = 0; j < 4; j++) boff[j] = (wn * 64 + j * 16 + l16) * 32 + quad * 8;

  for (int k0 = 0; k0 < Kd; k0 += 32) {
    __syncthreads();
    gl2lds16(gA0 + k0, lA0); gl2lds16(gA1 + k0, lA1);
    gl2lds16(gB0 + k0, lB0); gl2lds16(gB1 + k0, lB1);
    __syncthreads();
    bf16x8 fa[4], fb[4];
    #pragma unroll
    for (int i = 0; i < 4; i++) fa[i] = *(const bf16x8*)&sA[aoff[i]];
    #pragma unroll
    for (int j = 0; j < 4; j++) fb[j] = *(const bf16x8*)&sB[boff[j]];
    #pragma unroll
    for (int i = 0; i < 4; i++)
      #pragma unroll
      for (int j = 0; j < 4; j++)
        acc[i][j] = __builtin_amdgcn_mfma_f32_16x16x32_bf16(fa[i], fb[j], acc[i][j], 0, 0, 0);
  }

  #pragma unroll
  for (int i = 0; i < 4; i++)
    #pragma unroll
    for (int j = 0; j < 4; j++)
      #pragma unroll
      for (int r = 0; r < 4; r++) {
        float v = acc[i][j][r];
        long rr = row0 + wm * 64 + i * 16 + quad * 4 + r;
        long cc = n0 + wn * 64 + j * 16 + l16;
        if (outF) outF[rr * ldO + cc] = v;
        else      outB[rr * ldO + cc] = f2bf(v);
      }
}

// out[t,:] (holds shared fp32) += sum_k w[t,k] * dbuf[slot(t,k),:]
__global__ __launch_bounds__(256) void combine_k(
    const float* __restrict__ wtop, const int* __restrict__ slot_of,
    const u16* __restrict__ dbuf, float* __restrict__ out) {
  int t = blockIdx.x;
  int c = threadIdx.x * 8;
  long ob = (long)t * HDIM + c;
  float4 o0 = *(const float4*)&out[ob];
  float4 o1 = *(const float4*)&out[ob + 4];
  float acc[8] = {o0.x, o0.y, o0.z, o0.w, o1.x, o1.y, o1.z, o1.w};
  #pragma unroll
  for (int k = 0; k < TOPK; k++) {
    float w = wtop[t * TOPK + k];
    long s = slot_of[t * TOPK + k];
    const u16* dp = &dbuf[s * HDIM + c];
    ushort4 d0 = *(const ushort4*)dp;
    ushort4 d1 = *(const ushort4*)(dp + 4);
    acc[0] += w * bf2f(d0.x); acc[1] += w * bf2f(d0.y);
    acc[2] += w * bf2f(d0.z); acc[3] += w * bf2f(d0.w);
    acc[4] += w * bf2f(d1.x); acc[5] += w * bf2f(d1.y);
    acc[6] += w * bf2f(d1.z); acc[7] += w * bf2f(d1.w);
  }
  *(float4*)&out[ob]     = make_float4(acc[0], acc[1], acc[2], acc[3]);
  *(float4*)&out[ob + 4] = make_float4(acc[4], acc[5], acc[6], acc[7]);
}

// ---------------- host ----------------

extern "C" void kernel_launch(void* const* d_in, const int* in_sizes, int n_in,
                              void* d_out, int out_size, void* d_ws, size_t ws_size,
                              hipStream_t stream) {
  const float* x   = (const float*)d_in[0];
  const float* gw  = (const float*)d_in[1];
  const float* wg  = (const float*)d_in[2];
  const float* wu  = (const float*)d_in[3];
  const float* wd  = (const float*)d_in[4];
  const float* swg = (const float*)d_in[5];
  const float* swu = (const float*)d_in[6];
  const float* swd = (const float*)d_in[7];
  float* out = (float*)d_out;

  char* base = (char*)d_ws;
  size_t off = 0;
  auto alloc = [&](size_t bytes) -> char* {
    char* p = base + off;
    off = (off + bytes + 255) & ~(size_t)255;
    return p;
  };
  u16* wgT    = (u16*)alloc((size_t)NEXP * MDIM * HDIM * 2);
  u16* wuT    = (u16*)alloc((size_t)NEXP * MDIM * HDIM * 2);
  u16* wdT    = (u16*)alloc((size_t)NEXP * HDIM * MDIM * 2);
  u16* swgT   = (u16*)alloc((size_t)SHDIM * HDIM * 2);
  u16* swuT   = (u16*)alloc((size_t)SHDIM * HDIM * 2);
  u16* swdT   = (u16*)alloc((size_t)HDIM * SHDIM * 2);
  u16* xbf    = (u16*)alloc((size_t)TTOK * HDIM * 2);
  u16* hbuf   = (u16*)alloc((size_t)RCAP * MDIM * 2);
  u16* dbuf   = (u16*)alloc((size_t)RCAP * HDIM * 2);
  u16* hsbuf  = (u16*)alloc((size_t)TTOK * SHDIM * 2);
  float* wtop = (float*)alloc((size_t)TTOK * TOPK * 4);
  int* sel    = (int*)alloc((size_t)TTOK * TOPK * 4);
  int* slot_of= (int*)alloc((size_t)TTOK * TOPK * 4);
  int* rowTok = (int*)alloc((size_t)RCAP * 4);
  int* counts = (int*)alloc(NEXP * 4);
  int* cursor = (int*)alloc(NEXP * 4);
  int* padoff = (int*)alloc(NEXP * 4);
  int2* rtiles= (int2*)alloc(MAXRT * sizeof(int2));
  int2* stiles= (int2*)alloc((TTOK / 128) * sizeof(int2));
  if (off > ws_size) return;  // ws too small: fail loud (poison output)

  // 1) activations + weights -> bf16 ([n][k] transposed weights)
  cvt_f32_bf16<<<dim3((TTOK * HDIM) / 1024), 256, 0, stream>>>(x, xbf, (long)TTOK * HDIM);
  tcvt<<<dim3(MDIM / 32, HDIM / 32, NEXP), 256, 0, stream>>>(wg, wgT, HDIM, MDIM);
  tcvt<<<dim3(MDIM / 32, HDIM / 32, NEXP), 256, 0, stream>>>(wu, wuT, HDIM, MDIM);
  tcvt<<<dim3(HDIM / 32, MDIM / 32, NEXP), 256, 0, stream>>>(wd, wdT, MDIM, HDIM);
  tcvt<<<dim3(SHDIM / 32, HDIM / 32, 1), 256, 0, stream>>>(swg, swgT, HDIM, SHDIM);
  tcvt<<<dim3(SHDIM / 32, HDIM / 32, 1), 256, 0, stream>>>(swu, swuT, HDIM, SHDIM);
  tcvt<<<dim3(HDIM / 32, SHDIM / 32, 1), 256, 0, stream>>>(swd, swdT, SHDIM, HDIM);

  // 2) routing (exact fp32)
  zero32<<<1, 32, 0, stream>>>(counts);
  gate_route<<<dim3(TTOK / 4), 256, 0, stream>>>(x, gw, wtop, sel, counts);
  scan_k<<<1, 64, 0, stream>>>(counts, padoff, cursor, rtiles, stiles);
  fill_rt<<<dim3(RCAP / 256), 256, 0, stream>>>(rowTok);
  assign_k<<<dim3((TTOK * TOPK) / 256), 256, 0, stream>>>(sel, padoff, cursor, slot_of, rowTok);

  // 3) routed experts: h = silu(x@Wg)*(x@Wu); d = h@Wd
  gemm_gateup<<<dim3(MDIM / 128, MAXRT), 256, 0, stream>>>(
      xbf, rowTok, wgT, wuT, (long)MDIM * HDIM, hbuf, MDIM, HDIM, rtiles);
  gemm_down<<<dim3(HDIM / 128, MAXRT), 256, 0, stream>>>(
      hbuf, wdT, (long)HDIM * MDIM, dbuf, nullptr, HDIM, MDIM, rtiles);

  // 4) shared experts (down-proj writes fp32 straight into d_out)
  gemm_gateup<<<dim3(SHDIM / 128, TTOK / 128), 256, 0, stream>>>(
      xbf, nullptr, swgT, swuT, 0L, hsbuf, SHDIM, HDIM, stiles);
  gemm_down<<<dim3(HDIM / 128, TTOK / 128), 256, 0, stream>>>(
      hsbuf, swdT, 0L, nullptr, out, HDIM, SHDIM, stiles);

  // 5) combine: out += sum_k w_k * d[slot]
  combine_k<<<dim3(TTOK), 256, 0, stream>>>(wtop, slot_of, dbuf, out);
}